// Round 15
// baseline (539.019 us; speedup 1.0000x reference)
//
#include <hip/hip_runtime.h>
#include <hip/hip_bf16.h>

// ---------------------------------------------------------------------------
// Workspace layout (256 MiB):
//  [0,64MB)    : a_planar [b][cc64][f64][w128] bf16  -> reused as t2 (NHWC)
//  [64,128MB)  : a_nhwc   [b][h64][w128][cc64] bf16  -> reused as csumB in D2
//  [128,192MB) : t1_nhwc  [b][h64][w128][cc64] bf16
//  [192,..)    : csumA    [b][n32][h64][w121]  fp32  (60.5MB)
//                tail: AF (conv weight frags hi+lo, 720KB), WF (32KB),
//                BB (biases), wl2T (232KB)
//
// Real-ified complex conv: channels cc<32 = real, cc>=32 = imag.
// Wbig[o][cc]: o<32 (real out): [wr | -wi]; o>=32 (imag out): [wi | wr].
// All MFMA weights split-precision: part0 = bf16(w), part1 = bf16(w-part0).
// AF layout: [conv5][tap9][part2][ks2][mt4][lane64][j8] bf16.
//
// R15 = R14 + FULL-M WAVE TILE: each wave owns all 4 M-tiles (64 ch) x 4
// N-tiles (its own h-row x 64 w). Per tap-ks: 4 ds_read_b128 feed 32 MFMA
// (vs 8 feeding 16) -> block LDS reads halve (576->288), 8 MFMA of latency
// cover per read. acc 4x4x4=64 VGPR, peak ~150 VGPR -> no spill @ 2 blk/CU.
//  D1 (4096 blk): role j&1: conv1 d1 an->t1 | conv1 d2 an->t2   (mode 2)
//  D2 (4096 blk): role j&1: conv2 d1 t1 +=csumA | conv2 d2 t2 ->csumB
// ---------------------------------------------------------------------------

typedef __attribute__((ext_vector_type(8))) short bf16x8;
typedef __attribute__((ext_vector_type(4))) short bf16x4;
typedef __attribute__((ext_vector_type(4))) float f32x4;

__device__ __forceinline__ ushort f2bf(float v) {
  __hip_bfloat16 h = __float2bfloat16(v);
  return *reinterpret_cast<ushort*>(&h);
}
__device__ __forceinline__ float bf2f_raw(ushort u) {
  union { uint i; float f; } c; c.i = ((uint)u) << 16; return c.f;
}
__device__ __forceinline__ void split_bf(float v, ushort& h, ushort& l) {
  h = f2bf(v); l = f2bf(v - bf2f_raw(h));
}
__device__ __forceinline__ bf16x8 mk8(bf16x4 a, bf16x4 b) {
  bf16x8 r;
  r[0]=a[0]; r[1]=a[1]; r[2]=a[2]; r[3]=a[3];
  r[4]=b[0]; r[5]=b[1]; r[6]=b[2]; r[7]=b[3];
  return r;
}

#define MFMA16(A,B,C) __builtin_amdgcn_mfma_f32_16x16x32_bf16(A, B, C, 0, 0, 0)
#define SPMACC(acc, Ah, Al, Bh, Bl)      \
  acc = MFMA16(Ah, Bh, acc);             \
  acc = MFMA16(Al, Bh, acc);             \
  acc = MFMA16(Ah, Bl, acc);

// ---------------------------------------------------------------------------
// Kernel 1: fused STFT + QK^T + sigmoid + A, all via MFMA. Block = (b,n).
// ---------------------------------------------------------------------------
__global__ __launch_bounds__(512) void stft_mfma_k(const float* __restrict__ x,
                                                   const ushort* __restrict__ WF,
                                                   ushort* __restrict__ ap) {
  __shared__ __align__(16) char smem[133376];
  const int bid = blockIdx.x;
  const int b = bid >> 5, n = bid & 31;
  const int tid = threadIdx.x;
  ushort* xph = reinterpret_cast<ushort*>(smem + 131072);
  ushort* xpl = xph + 576;

  for (int i = tid; i < 576; i += 512) {
    float v = 0.f;
    if (i < 544) {
      int p = i - 32;
      if (p < 0) p = -p;
      if (p >= 480) p = 958 - p;
      v = x[(b * 480 + p) * 32 + n];
    }
    ushort h, l; split_bf(v, h, l);
    xph[i] = h; xpl[i] = l;
  }
  __syncthreads();

  const int wv = tid >> 6, lane = tid & 63;
  const int mt = wv >> 1, nth = wv & 1;
  const int l15 = lane & 15, l4 = lane >> 4;

  bf16x8 WA[2][2][2];  // [cs][part][ks]
#pragma unroll
  for (int cs = 0; cs < 2; ++cs)
#pragma unroll
    for (int part = 0; part < 2; ++part)
#pragma unroll
      for (int ks = 0; ks < 2; ++ks)
        WA[cs][part][ks] = *reinterpret_cast<const bf16x8*>(
            WF + (((cs * 2 + part) * 2 + ks) * 4 + mt) * 512 + lane * 8);

  f32x4 acc1[2][4];
#pragma unroll
  for (int cs = 0; cs < 2; ++cs)
#pragma unroll
    for (int nt = 0; nt < 4; ++nt) acc1[cs][nt] = (f32x4){0.f, 0.f, 0.f, 0.f};

#pragma unroll
  for (int ks = 0; ks < 2; ++ks) {
    bf16x8 bh[4], bl[4];
#pragma unroll
    for (int nt = 0; nt < 4; ++nt) {
      int n_ = ((nth * 4 + nt) * 16) + l15;
      int e = n_ * 4 + ks * 32 + l4 * 8;
      bf16x4 h0 = *reinterpret_cast<const bf16x4*>(xph + e);
      bf16x4 h1 = *reinterpret_cast<const bf16x4*>(xph + e + 4);
      bf16x4 l0 = *reinterpret_cast<const bf16x4*>(xpl + e);
      bf16x4 l1 = *reinterpret_cast<const bf16x4*>(xpl + e + 4);
      bh[nt] = mk8(h0, h1); bl[nt] = mk8(l0, l1);
    }
#pragma unroll
    for (int cs = 0; cs < 2; ++cs)
#pragma unroll
      for (int nt = 0; nt < 4; ++nt) {
        SPMACC(acc1[cs][nt], WA[cs][0][ks], WA[cs][1][ks], bh[nt], bl[nt]);
      }
  }

#pragma unroll
  for (int cs = 0; cs < 2; ++cs)
#pragma unroll
    for (int nt = 0; nt < 4; ++nt) {
      int k = (nth * 4 + nt) * 16 + l15;
      bool kv = (k < 121);
#pragma unroll
      for (int r = 0; r < 4; ++r) {
        int f = mt * 16 + l4 * 4 + r;
        float v = kv ? acc1[cs][nt][r] : 0.f;
        ushort h, l; split_bf(v, h, l);
        int ba = (f << 8) + (k << 1); ba ^= (f & 7) << 4;
        *reinterpret_cast<ushort*>(smem + cs * 32768 + ba) = h;
        *reinterpret_cast<ushort*>(smem + cs * 32768 + 16384 + ba) = l;
        int bt = (k << 7) + (f << 1); bt ^= (k & 7) << 4;
        *reinterpret_cast<ushort*>(smem + 65536 + cs * 32768 + bt) = h;
        *reinterpret_cast<ushort*>(smem + 65536 + cs * 32768 + 16384 + bt) = l;
      }
    }
  __syncthreads();

  f32x4 acc2[2][4];  // [nt][rr, ii, ri, ir]
#pragma unroll
  for (int nt = 0; nt < 2; ++nt)
#pragma unroll
    for (int c = 0; c < 4; ++c) acc2[nt][c] = (f32x4){0.f, 0.f, 0.f, 0.f};

#pragma unroll
  for (int ks = 0; ks < 4; ++ks) {
    bf16x8 A_[2][2];
#pragma unroll
    for (int comp = 0; comp < 2; ++comp)
#pragma unroll
      for (int part = 0; part < 2; ++part) {
        int f = mt * 16 + l15;
        int ba = (f << 8) + ((ks * 32 + l4 * 8) << 1); ba ^= (f & 7) << 4;
        A_[comp][part] = *reinterpret_cast<const bf16x8*>(smem + comp * 32768 + part * 16384 + ba);
      }
    bf16x8 B_[2][2][2];
#pragma unroll
    for (int comp = 0; comp < 2; ++comp)
#pragma unroll
      for (int part = 0; part < 2; ++part)
#pragma unroll
        for (int nt = 0; nt < 2; ++nt) {
          int g = (nth * 2 + nt) * 16 + l15;
          int ba = (g << 8) + ((ks * 32 + l4 * 8) << 1); ba ^= (g & 7) << 4;
          B_[comp][part][nt] = *reinterpret_cast<const bf16x8*>(smem + comp * 32768 + part * 16384 + ba);
        }
#pragma unroll
    for (int nt = 0; nt < 2; ++nt) {
      SPMACC(acc2[nt][0], A_[0][0], A_[0][1], B_[0][0][nt], B_[0][1][nt]);
      SPMACC(acc2[nt][1], A_[1][0], A_[1][1], B_[1][0][nt], B_[1][1][nt]);
      SPMACC(acc2[nt][2], A_[0][0], A_[0][1], B_[1][0][nt], B_[1][1][nt]);
      SPMACC(acc2[nt][3], A_[1][0], A_[1][1], B_[0][0][nt], B_[0][1][nt]);
    }
  }
  __syncthreads();

#pragma unroll
  for (int nt = 0; nt < 2; ++nt) {
    int g = (nth * 2 + nt) * 16 + l15;
#pragma unroll
    for (int r = 0; r < 4; ++r) {
      int f = mt * 16 + l4 * 4 + r;
      float qr = acc2[nt][0][r] - acc2[nt][1][r];
      float qi = acc2[nt][2][r] + acc2[nt][3][r];
      float vr = 1.f / (1.f + __expf(-qr));
      float vi = 1.f / (1.f + __expf(-qi));
      int ba = (f << 7) + (g << 1); ba ^= (f & 7) << 4;
      ushort h, l;
      split_bf(vr, h, l);
      *reinterpret_cast<ushort*>(smem + ba) = h;
      *reinterpret_cast<ushort*>(smem + 8192 + ba) = l;
      split_bf(vi, h, l);
      *reinterpret_cast<ushort*>(smem + 16384 + ba) = h;
      *reinterpret_cast<ushort*>(smem + 24576 + ba) = l;
    }
  }
  __syncthreads();

  f32x4 acc3[4][3];
#pragma unroll
  for (int nt = 0; nt < 4; ++nt)
#pragma unroll
    for (int c = 0; c < 3; ++c) acc3[nt][c] = (f32x4){0.f, 0.f, 0.f, 0.f};

#pragma unroll
  for (int ks = 0; ks < 2; ++ks) {
    bf16x8 QA[2][2];
#pragma unroll
    for (int comp = 0; comp < 2; ++comp)
#pragma unroll
      for (int part = 0; part < 2; ++part) {
        int f = mt * 16 + l15;
        int ba = (f << 7) + ((ks * 32 + l4 * 8) << 1); ba ^= (f & 7) << 4;
        QA[comp][part] = *reinterpret_cast<const bf16x8*>(smem + comp * 16384 + part * 8192 + ba);
      }
#pragma unroll
    for (int nt = 0; nt < 4; ++nt) {
      int k = (nth * 4 + nt) * 16 + l15;
      int bq = (k << 7) + ((ks * 32 + l4 * 8) << 1); bq ^= (k & 7) << 4;
      bf16x8 Srh = *reinterpret_cast<const bf16x8*>(smem + 65536 + bq);
      bf16x8 Srl = *reinterpret_cast<const bf16x8*>(smem + 81920 + bq);
      bf16x8 Sih = *reinterpret_cast<const bf16x8*>(smem + 98304 + bq);
      bf16x8 Sil = *reinterpret_cast<const bf16x8*>(smem + 114688 + bq);
      SPMACC(acc3[nt][0], QA[0][0], QA[0][1], Srh, Srl);
      SPMACC(acc3[nt][1], QA[1][0], QA[1][1], Sih, Sil);
      SPMACC(acc3[nt][2], QA[0][0], QA[0][1], Sih, Sil);
      SPMACC(acc3[nt][2], QA[1][0], QA[1][1], Srh, Srl);
    }
  }
  __syncthreads();

#pragma unroll
  for (int nt = 0; nt < 4; ++nt) {
    int k = (nth * 4 + nt) * 16 + l15;
#pragma unroll
    for (int r = 0; r < 4; ++r) {
      int f = mt * 16 + l4 * 4 + r;
      float ar = acc3[nt][0][r] - acc3[nt][1][r];
      float ai = acc3[nt][2][r];
      int ba = (f << 8) + (k << 1); ba ^= (f & 7) << 4;
      *reinterpret_cast<ushort*>(smem + ba) = f2bf(ar);
      *reinterpret_cast<ushort*>(smem + 16384 + ba) = f2bf(ai);
    }
  }
  __syncthreads();

  uint4* dst = reinterpret_cast<uint4*>(ap);
  for (int i = tid; i < 2048; i += 512) {
    int comp = i >> 10, rem = i & 1023;
    int f = rem >> 4, q = rem & 15;
    uint4 v = *reinterpret_cast<const uint4*>(
        smem + comp * 16384 + (f << 8) + ((q ^ (f & 7)) << 4));
    dst[((size_t)(b * 64 + n + 32 * comp) * 64) * 16 + rem] = v;
  }
}

// ---------------------------------------------------------------------------
// Kernel 2: transpose a_planar -> a_nhwc, FUSED with conv0 (1x1) -> csumA init.
// ---------------------------------------------------------------------------
__global__ __launch_bounds__(256) void transpose_k(const ushort* __restrict__ ap,
    ushort* __restrict__ an, const ushort* __restrict__ AF,
    const float* __restrict__ BB, const float* __restrict__ wl0,
    float* __restrict__ csumA) {
  __shared__ __align__(16) ushort T[64 * 128];
  const int b = blockIdx.x >> 6, h = blockIdx.x & 63;
  const int tid = threadIdx.x;
#pragma unroll
  for (int it = 0; it < 4; ++it) {
    int i = it * 256 + tid;
    int cc = i >> 4, q = i & 15;
    const uint4* src = reinterpret_cast<const uint4*>(ap) +
                       ((size_t)((b * 64 + cc) * 64 + h) * 16 + q);
    *reinterpret_cast<uint4*>(&T[cc * 128 + q * 8]) = *src;
  }
  __syncthreads();
  const int p = tid >> 1, cc0 = (tid & 1) * 32;
  uint ou[16];
#pragma unroll
  for (int it = 0; it < 16; ++it) {
    uint lo = T[(cc0 + 2 * it) * 128 + p];
    uint hi = T[(cc0 + 2 * it + 1) * 128 + p];
    ou[it] = lo | (hi << 16);
  }
  uint4* dst = reinterpret_cast<uint4*>(an + ((size_t)((b * 64 + h) * 128 + p) * 64 + cc0));
#pragma unroll
  for (int r = 0; r < 4; ++r) dst[r] = make_uint4(ou[4*r], ou[4*r+1], ou[4*r+2], ou[4*r+3]);
  __syncthreads();   // all T reads done before overwrite

  // re-stage swizzled [w128][cc64] (conv staging layout) into T's memory
  char* S = reinterpret_cast<char*>(T);
#pragma unroll
  for (int it = 0; it < 16; ++it) {
    int byt = p * 128 + (cc0 + 2 * it) * 2;
    byt ^= (p & 7) << 4;
    *reinterpret_cast<uint*>(S + byt) = ou[it];
  }
  __syncthreads();

  // conv0 MFMA (weights AF conv0, split hi/lo) -> csumA init
  const int wave = tid >> 6, lane = tid & 63;
  const int mtb = wave & 1, ntb = (wave >> 1) * 4;
  const int l15 = lane & 15, l4 = lane >> 4;
  const ushort* Ab = AF + lane * 8;
  bf16x8 AH[2][2], AL[2][2];
#pragma unroll
  for (int ks = 0; ks < 2; ++ks)
#pragma unroll
    for (int mi = 0; mi < 2; ++mi) {
      AH[ks][mi] = *reinterpret_cast<const bf16x8*>(Ab + ks * 2048 + (mtb + 2 * mi) * 512);
      AL[ks][mi] = *reinterpret_cast<const bf16x8*>(Ab + 4096 + ks * 2048 + (mtb + 2 * mi) * 512);
    }
  f32x4 acc[2][4];
#pragma unroll
  for (int mi = 0; mi < 2; ++mi)
#pragma unroll
    for (int nt = 0; nt < 4; ++nt) acc[mi][nt] = (f32x4){0.f, 0.f, 0.f, 0.f};
#pragma unroll
  for (int ks = 0; ks < 2; ++ks) {
    bf16x8 bv[4];
#pragma unroll
    for (int nt = 0; nt < 4; ++nt) {
      int w = (ntb + nt) * 16 + l15;
      int byt = w * 128 + ks * 64 + l4 * 16;
      byt ^= (w & 7) << 4;
      bv[nt] = *reinterpret_cast<const bf16x8*>(S + byt);
    }
#pragma unroll
    for (int nt = 0; nt < 4; ++nt) {
      acc[0][nt] = MFMA16(AH[ks][0], bv[nt], acc[0][nt]);
      acc[1][nt] = MFMA16(AH[ks][1], bv[nt], acc[1][nt]);
    }
#pragma unroll
    for (int nt = 0; nt < 4; ++nt) {
      acc[0][nt] = MFMA16(AL[ks][0], bv[nt], acc[0][nt]);
      acc[1][nt] = MFMA16(AL[ks][1], bv[nt], acc[1][nt]);
    }
  }
  const float w00 = wl0[0], w01 = wl0[1];
#pragma unroll
  for (int nt = 0; nt < 4; ++nt) {
    int gw = (ntb + nt) * 16 + l15;
    if (gw < 121) {
#pragma unroll
      for (int r = 0; r < 4; ++r) {
        int n = mtb * 16 + l4 * 4 + r;
        float rr = acc[0][nt][r] + BB[n];
        float im = acc[1][nt][r] + BB[n + 32];
        csumA[((size_t)(b * 32 + n) * 64 + h) * 121 + gw] =
            (fmaxf(rr, 0.f) * w00 + fmaxf(im, 0.f) * w01) * (1.f / 3.f);
      }
    }
  }
}

// ---------------------------------------------------------------------------
// Kernel 3: prep (unchanged).
// ---------------------------------------------------------------------------
__global__ __launch_bounds__(256) void prep_k(
    const float* __restrict__ w0r, const float* __restrict__ w0i,
    const float* __restrict__ b0r, const float* __restrict__ b0i,
    const float* __restrict__ W1r, const float* __restrict__ W1i,
    const float* __restrict__ B1r, const float* __restrict__ B1i,
    const float* __restrict__ W2r, const float* __restrict__ W2i,
    const float* __restrict__ B2r, const float* __restrict__ B2i,
    const float* __restrict__ wl2,
    ushort* __restrict__ AF, ushort* __restrict__ WF, float* __restrict__ BB,
    float* __restrict__ wl2T) {
  const int blk = blockIdx.x, tid = threadIdx.x;
  const float PI32 = 0.0981747704246810387f;

  if (blk == 38) {
    for (int i = tid; i < 121 * 480; i += 256) {
      int k = i / 480, t = i - k * 480;
      wl2T[i] = wl2[t * 121 + k];
    }
    return;
  }
  if (blk == 37) {
    for (int i = tid; i < 16384; i += 256) {
      int j = i & 7, ln = (i >> 3) & 63, mt = (i >> 9) & 3, ks = (i >> 11) & 1;
      int part = (i >> 12) & 1, cs = (i >> 13) & 1;
      int f = mt * 16 + (ln & 15);
      int t = ks * 32 + (ln >> 4) * 8 + j;
      float win = 0.5f * (1.0f - __cosf(PI32 * (float)t));
      int m = (f * t) & 63;
      float sv, cv;
      __sincosf(PI32 * (float)m, &sv, &cv);
      float val = (cs == 0) ? (win * cv * 0.125f) : (-win * sv * 0.125f);
      ushort h = f2bf(val);
      WF[i] = part ? f2bf(val - bf2f_raw(h)) : h;
    }
    return;
  }

  int conv, tap, TT;
  const float *Wr, *Wi;
  if (blk == 0) { conv = 0; tap = 0; TT = 1; Wr = w0r; Wi = w0i; }
  else {
    int q = blk - 1; conv = 1 + q / 9; tap = q - (q / 9) * 9; TT = 9;
    if (conv == 1)      { Wr = W1r;        Wi = W1i; }
    else if (conv == 2) { Wr = W2r;        Wi = W2i; }
    else if (conv == 3) { Wr = W1r + 9216; Wi = W1i + 9216; }
    else                { Wr = W2r + 9216; Wi = W2i + 9216; }
  }
  ushort thi[16], tlo[16];
#pragma unroll
  for (int jj = 0; jj < 16; ++jj) {
    int e = tid * 16 + jj;
    int j = e & 7, lane_e = (e >> 3) & 63, mt = (e >> 9) & 3, ks = (e >> 11) & 1;
    int o  = mt * 16 + (lane_e & 15);
    int cc = ks * 32 + 8 * (lane_e >> 4) + j;
    int ci = cc & 31, ch = cc >> 5, on = o & 31, oh = o >> 5;
    float wr = Wr[(on * 32 + ci) * TT + tap];
    float wi = Wi[(on * 32 + ci) * TT + tap];
    float v = (oh == 0) ? (ch == 0 ? wr : -wi) : (ch == 0 ? wi : wr);
    ushort h = f2bf(v);
    thi[jj] = h;
    tlo[jj] = f2bf(v - bf2f_raw(h));
  }
  ushort* base = AF + conv * 73728 + tap * 8192 + tid * 16;
  uint4* dh = reinterpret_cast<uint4*>(base);
  uint4* dl = reinterpret_cast<uint4*>(base + 4096);
  dh[0] = *reinterpret_cast<uint4*>(&thi[0]);
  dh[1] = *reinterpret_cast<uint4*>(&thi[8]);
  dl[0] = *reinterpret_cast<uint4*>(&tlo[0]);
  dl[1] = *reinterpret_cast<uint4*>(&tlo[8]);

  if (blk == 0) {
    for (int i = tid; i < 320; i += 256) {
      int c = i >> 6, o = i & 63;
      const float *br, *bi;
      if (c == 0)      { br = b0r;      bi = b0i; }
      else if (c == 1) { br = B1r;      bi = B1i; }
      else if (c == 2) { br = B2r;      bi = B2i; }
      else if (c == 3) { br = B1r + 32; bi = B1i + 32; }
      else             { br = B2r + 32; bi = B2i + 32; }
      BB[c * 64 + o] = (o < 32) ? (br[o] - bi[o]) : (br[o - 32] + bi[o - 32]);
    }
  }
}

// ---------------------------------------------------------------------------
// Conv (R15): 8 LDS row buffers [68 bw][64 cc] bf16, swizzle ^(bw&7)<<4.
// Buffer r holds input row h0 + r - 2. Block output: 64ch x 4h x 64w.
// Wave tile: FULL M (4 mt = 64 ch) x 4 nt (wave's h-row x 64 w).
// Per tap-ks: 4 ds_read_b128 shared by 32 MFMA.
// ---------------------------------------------------------------------------
#define RWB 8704

__device__ __forceinline__ void run_taps9(const char* __restrict__ smem,
    const ushort* __restrict__ afrag, int d,
    int jrow, int l15, int l4, int lane, f32x4 acc[4][4]) {
  const ushort* Ab = afrag + lane * 8;
#pragma unroll
  for (int t = 0; t < 9; ++t) {
    const int dy = t / 3;
    const int dxo = ((t - dy * 3) - 1) * d;
    const int buf = (dy - 1) * d + 2 + jrow;      // in [0,8)
    const ushort* At = Ab + t * 8192;
#pragma unroll
    for (int ks = 0; ks < 2; ++ks) {
      bf16x8 AH[4], AL[4];
#pragma unroll
      for (int mt = 0; mt < 4; ++mt) {
        AH[mt] = *reinterpret_cast<const bf16x8*>(At + ks * 2048 + mt * 512);
        AL[mt] = *reinterpret_cast<const bf16x8*>(At + 4096 + ks * 2048 + mt * 512);
      }
      bf16x8 bv[4];
#pragma unroll
      for (int nt = 0; nt < 4; ++nt) {
        int bw = nt * 16 + l15 + dxo + 2;         // in [0,68)
        int byt = buf * RWB + bw * 128 + ks * 64 + l4 * 16;
        byt ^= (bw & 7) << 4;
        bv[nt] = *reinterpret_cast<const bf16x8*>(smem + byt);
      }
      __builtin_amdgcn_s_setprio(1);
#pragma unroll
      for (int nt = 0; nt < 4; ++nt)
#pragma unroll
        for (int mt = 0; mt < 4; ++mt)
          acc[mt][nt] = MFMA16(AH[mt], bv[nt], acc[mt][nt]);
#pragma unroll
      for (int nt = 0; nt < 4; ++nt)
#pragma unroll
        for (int mt = 0; mt < 4; ++mt)
          acc[mt][nt] = MFMA16(AL[mt], bv[nt], acc[mt][nt]);
      __builtin_amdgcn_s_setprio(0);
    }
  }
}

__device__ __forceinline__ void conv_body3(char* smem,
    const ushort* __restrict__ xin, ushort* __restrict__ tout,
    const ushort* __restrict__ afrag, const float* __restrict__ bb,
    const float* __restrict__ wl0, float* __restrict__ csum,
    int d, int b, int h0, int side, int mode, int tid) {
  const int jrow = tid >> 6, lane = tid & 63;   // wave = its own h row
  const int l15 = lane & 15, l4 = lane >> 4;
  const int wbase = side * 64;

  // ---- BATCHED staging: issue all 24 loads, then all writes ----
  {
    uint4 st[8][3];
#pragma unroll
    for (int r = 0; r < 8; ++r) {
      const int hh = h0 + r - 2;
      const bool hv = ((unsigned)hh < 64u);
      const ushort* rowp = xin + ((size_t)(b * 64 + hh) << 13);
#pragma unroll
      for (int c = 0; c < 3; ++c) {
        int i = c * 256 + tid;
        uint4 v = make_uint4(0u, 0u, 0u, 0u);
        if (i < 544) {
          int bw = i >> 3, q = i & 7;
          int gw = wbase + bw - 2;
          if (hv && (unsigned)gw < 128u)
            v = *reinterpret_cast<const uint4*>(rowp + (size_t)gw * 64 + q * 8);
        }
        st[r][c] = v;
      }
    }
#pragma unroll
    for (int r = 0; r < 8; ++r)
#pragma unroll
      for (int c = 0; c < 3; ++c) {
        int i = c * 256 + tid;
        if (i < 544) {
          int bw = i >> 3, q = i & 7;
          int byt = r * RWB + bw * 128 + q * 16;
          byt ^= (bw & 7) << 4;
          *reinterpret_cast<uint4*>(smem + byt) = st[r][c];
        }
      }
  }
  __syncthreads();

  f32x4 acc[4][4];
#pragma unroll
  for (int mt = 0; mt < 4; ++mt)
#pragma unroll
    for (int nt = 0; nt < 4; ++nt) acc[mt][nt] = (f32x4){0.f, 0.f, 0.f, 0.f};

  run_taps9(smem, afrag, d, jrow, l15, l4, lane, acc);

  if (mode == 2) {
    __syncthreads();                       // row buffers free -> bounce
    uint* Lb = reinterpret_cast<uint*>(smem);  // [4 jrow][32 opair][66]
#pragma unroll
    for (int mt = 0; mt < 4; ++mt) {
#pragma unroll
      for (int rp = 0; rp < 2; ++rp) {
        int o = mt * 16 + l4 * 4 + rp * 2;
        float b0 = bb[o], b1 = bb[o + 1];
#pragma unroll
        for (int nt = 0; nt < 4; ++nt) {
          int wl = nt * 16 + l15;
          uint pk = (uint)f2bf(acc[mt][nt][rp * 2] + b0) |
                    ((uint)f2bf(acc[mt][nt][rp * 2 + 1] + b1) << 16);
          Lb[(jrow * 32 + (o >> 1)) * 66 + wl] = pk;
        }
      }
    }
    __syncthreads();
#pragma unroll
    for (int c = 0; c < 8; ++c) {
      int i = c * 256 + tid;           // 2048 uint4 = 4h x 64w x 64cc
      int jr = i >> 9, rem = i & 511;
      int wl = rem >> 3, q = rem & 7;
      int gw = wbase + wl;
      int hh = h0 + jr;
      bool val = (gw < 121);
      uint4 v;
      v.x = val ? Lb[(jr * 32 + q * 4 + 0) * 66 + wl] : 0u;
      v.y = val ? Lb[(jr * 32 + q * 4 + 1) * 66 + wl] : 0u;
      v.z = val ? Lb[(jr * 32 + q * 4 + 2) * 66 + wl] : 0u;
      v.w = val ? Lb[(jr * 32 + q * 4 + 3) * 66 + wl] : 0u;
      *reinterpret_cast<uint4*>(
          tout + (((size_t)(b * 64 + hh) * 128 + gw) * 64 + q * 8)) = v;
    }
  } else {
    const float w00 = wl0[0], w01 = wl0[1];
    const int hh = h0 + jrow;
#pragma unroll
    for (int mt = 0; mt < 2; ++mt) {
#pragma unroll
      for (int nt = 0; nt < 4; ++nt) {
        int gw = wbase + nt * 16 + l15;
        if (gw < 121) {
#pragma unroll
          for (int r = 0; r < 4; ++r) {
            int n = mt * 16 + l4 * 4 + r;
            float rr = acc[mt][nt][r] + bb[n];
            float im = acc[mt + 2][nt][r] + bb[n + 32];
            float v = (fmaxf(rr, 0.f) * w00 + fmaxf(im, 0.f) * w01) * (1.f / 3.f);
            float* p = csum + ((size_t)(b * 32 + n) * 64 + hh) * 121 + gw;
            if (mode == 1) v += *p;
            *p = v;
          }
        }
      }
    }
  }
}

// D1 (4096 blk): x=bid&7 (XCD), j=bid>>3 (<512): role=j&1, sub=j>>1 (<256),
// wg=(x<<8)|sub -> b=wg>>5, h0, side. Roles+sides adjacent on same XCD.
__global__ __launch_bounds__(256, 2) void convD1_k(
    const ushort* __restrict__ an, ushort* __restrict__ t1, ushort* __restrict__ t2,
    const ushort* __restrict__ AF, const float* __restrict__ BB,
    const float* __restrict__ wl0) {
  __shared__ __align__(16) char smem[8 * RWB];
  const int x = blockIdx.x & 7, j = blockIdx.x >> 3;
  const int role = j & 1, sub = j >> 1;
  const int wg = (x << 8) | sub;
  const int b = wg >> 5, rem = wg & 31;
  const int h0 = ((rem >> 1) & 15) * 4, side = rem & 1;
  const int tid = threadIdx.x;
  if (role == 0)
    conv_body3(smem, an, t1, AF + 1 * 73728, BB + 64, wl0, nullptr, 1, b, h0, side, 2, tid);
  else
    conv_body3(smem, an, t2, AF + 3 * 73728, BB + 192, wl0, nullptr, 2, b, h0, side, 2, tid);
}

// D2 (4096 blk): same decode. role0: conv2d1 t1 +=csumA; role1: conv2d2 t2 ->csumB.
__global__ __launch_bounds__(256, 2) void convD2_k(
    const ushort* __restrict__ t1, const ushort* __restrict__ t2,
    const ushort* __restrict__ AF, const float* __restrict__ BB,
    const float* __restrict__ wl0, float* __restrict__ csumA,
    float* __restrict__ csumB) {
  __shared__ __align__(16) char smem[8 * RWB];
  const int x = blockIdx.x & 7, j = blockIdx.x >> 3;
  const int role = j & 1, sub = j >> 1;
  const int wg = (x << 8) | sub;
  const int b = wg >> 5, rem = wg & 31;
  const int h0 = ((rem >> 1) & 15) * 4, side = rem & 1;
  const int tid = threadIdx.x;
  if (role == 0)
    conv_body3(smem, t1, nullptr, AF + 2 * 73728, BB + 128, wl0, csumA, 1, b, h0, side, 1, tid);
  else
    conv_body3(smem, t2, nullptr, AF + 4 * 73728, BB + 256, wl0, csumB, 2, b, h0, side, 0, tid);
}

// ---------------------------------------------------------------------------
// Kernel 5: epilogue. h[k] = mean_f(csumA+csumB) + b_l0 ; y = h @ w_l2T + b_l2
// ---------------------------------------------------------------------------
__global__ __launch_bounds__(256) void epi_k(const float* __restrict__ csumA,
    const float* __restrict__ csumB,
    const float* __restrict__ bl0, const float* __restrict__ wl2T,
    const float* __restrict__ bl2, float* __restrict__ out) {
  const int b = blockIdx.x >> 5, n = blockIdx.x & 31;
  __shared__ float sh[121];
  const int tid = threadIdx.x;
  const float* baseA = csumA + (size_t)(b * 32 + n) * 64 * 121;
  const float* baseB = csumB + (size_t)(b * 32 + n) * 64 * 121;
  for (int k = tid; k < 121; k += 256) {
    float s = 0.f;
#pragma unroll 8
    for (int f = 0; f < 64; ++f) s += baseA[f * 121 + k] + baseB[f * 121 + k];
    sh[k] = s * (1.f / 64.f) + bl0[0];
  }
  __syncthreads();
  for (int t = tid; t < 480; t += 256) {
    float acc = bl2[t];
#pragma unroll 8
    for (int k = 0; k < 121; ++k) acc = fmaf(sh[k], wl2T[k * 480 + t], acc);
    out[(b * 480 + t) * 32 + n] = acc;
  }
}

// ---------------------------------------------------------------------------
extern "C" void kernel_launch(void* const* d_in, const int* in_sizes, int n_in,
                              void* d_out, int out_size, void* d_ws, size_t ws_size,
                              hipStream_t stream) {
  const float* x   = (const float*)d_in[0];
  const float* w0r = (const float*)d_in[1];
  const float* w0i = (const float*)d_in[2];
  const float* b0r = (const float*)d_in[3];
  const float* b0i = (const float*)d_in[4];
  const float* W1r = (const float*)d_in[5];
  const float* W1i = (const float*)d_in[6];
  const float* B1r = (const float*)d_in[7];
  const float* B1i = (const float*)d_in[8];
  const float* W2r = (const float*)d_in[9];
  const float* W2i = (const float*)d_in[10];
  const float* B2r = (const float*)d_in[11];
  const float* B2i = (const float*)d_in[12];
  const float* wl0 = (const float*)d_in[13];
  const float* bl0 = (const float*)d_in[14];
  const float* wl2 = (const float*)d_in[15];
  const float* bl2 = (const float*)d_in[16];

  char* ws = (char*)d_ws;
  const size_t MB64 = (size_t)64 << 20;
  ushort* ap    = (ushort*)ws;                       // a_planar -> t2 later
  ushort* t2    = (ushort*)ws;
  ushort* an    = (ushort*)(ws + MB64);              // a_nhwc -> csumB later
  float*  csumB = (float*)(ws + MB64);
  ushort* t1    = (ushort*)(ws + 2 * MB64);
  float*  csumA = (float*)(ws + 3 * MB64);           // [b][32][64][121] fp32
  const size_t CSZ = (size_t)64 * 32 * 64 * 121 * 4; // 63,438,848 B
  ushort* AF   = (ushort*)(ws + 3 * MB64 + CSZ);     // 737,280 B
  ushort* WFp  = AF + 5 * 73728;                     // 32,768 B
  float*  BB   = (float*)(WFp + 16384);              // 1,280 B
  float*  wl2T = BB + 320;                           // 232,320 B
  float*  out  = (float*)d_out;

  hipLaunchKernelGGL(prep_k, dim3(39), dim3(256), 0, stream,
                     w0r, w0i, b0r, b0i, W1r, W1i, B1r, B1i, W2r, W2i, B2r, B2i,
                     wl2, AF, WFp, BB, wl2T);
  hipLaunchKernelGGL(stft_mfma_k, dim3(2048), dim3(512), 0, stream, x, WFp, ap);
  // transpose + fused conv0 -> csumA init
  hipLaunchKernelGGL(transpose_k, dim3(4096), dim3(256), 0, stream,
                     ap, an, AF, BB, wl0, csumA);
  // D1: conv1(d=1) -> t1 ; conv1(d=2) -> t2 (overwrites ap)
  hipLaunchKernelGGL(convD1_k, dim3(4096), dim3(256), 0, stream,
                     an, t1, t2, AF, BB, wl0);
  // D2: conv2(d=1) += csumA ; conv2(d=2) -> csumB (overwrites an)
  hipLaunchKernelGGL(convD2_k, dim3(4096), dim3(256), 0, stream,
                     t1, t2, AF, BB, wl0, csumA, csumB);
  hipLaunchKernelGGL(epi_k, dim3(2048), dim3(256), 0, stream,
                     csumA, csumB, bl0, wl2T, bl2, out);
}

// Round 16
// 485.141 us; speedup vs baseline: 1.1111x; 1.1111x over previous
//
#include <hip/hip_runtime.h>
#include <hip/hip_bf16.h>

// ---------------------------------------------------------------------------
// Workspace layout (256 MiB):
//  [0,64MB)    : a_planar [b][cc64][f64][w128] bf16  -> reused as t2 (NHWC)
//  [64,128MB)  : a_nhwc   [b][h64][w128][cc64] bf16  -> reused as csumB in D2
//  [128,192MB) : t1_nhwc  [b][h64][w128][cc64] bf16
//  [192,..)    : csumA    [b][n32][h64][w121]  fp32  (60.5MB)
//                tail: AF (conv weight frags hi+lo, 720KB), WF (32KB),
//                BB (biases), wl2T (232KB), ZP (64B zero page)
//
// Real-ified complex conv: channels cc<32 = real, cc>=32 = imag.
// Wbig[o][cc]: o<32 (real out): [wr | -wi]; o>=32 (imag out): [wi | wr].
// All MFMA weights split-precision: part0 = bf16(w), part1 = bf16(w-part0).
// AF layout: [conv5][tap9][part2][ks2][mt4][lane64][j8] bf16.
//
// R16 = R14 (best known, 2mt x 8nt wave tile) + GLOBAL_LOAD_LDS staging:
// direct HBM->LDS (width 16), LDS dest LINEAR (wave-uniform base + lane*16),
// XOR swizzle moved to the per-lane GLOBAL source address (involution, m173
// pattern); read side keeps its XOR -> identical data layout. OOB lanes load
// from a zeroed 64B page. Removes the 96-VGPR reg-staging + drain.
//  D1 (4096 blk): role j&1: conv1 d1 an->t1 | conv1 d2 an->t2   (mode 2)
//  D2 (4096 blk): role j&1: conv2 d1 t1 +=csumA | conv2 d2 t2 ->csumB
// ---------------------------------------------------------------------------

typedef __attribute__((ext_vector_type(8))) short bf16x8;
typedef __attribute__((ext_vector_type(4))) short bf16x4;
typedef __attribute__((ext_vector_type(4))) float f32x4;

__device__ __forceinline__ ushort f2bf(float v) {
  __hip_bfloat16 h = __float2bfloat16(v);
  return *reinterpret_cast<ushort*>(&h);
}
__device__ __forceinline__ float bf2f_raw(ushort u) {
  union { uint i; float f; } c; c.i = ((uint)u) << 16; return c.f;
}
__device__ __forceinline__ void split_bf(float v, ushort& h, ushort& l) {
  h = f2bf(v); l = f2bf(v - bf2f_raw(h));
}
__device__ __forceinline__ bf16x8 mk8(bf16x4 a, bf16x4 b) {
  bf16x8 r;
  r[0]=a[0]; r[1]=a[1]; r[2]=a[2]; r[3]=a[3];
  r[4]=b[0]; r[5]=b[1]; r[6]=b[2]; r[7]=b[3];
  return r;
}
__device__ __forceinline__ void gld16(const ushort* g, char* lds) {
  __builtin_amdgcn_global_load_lds(
      (const __attribute__((address_space(1))) void*)g,
      (__attribute__((address_space(3))) void*)lds, 16, 0, 0);
}

#define MFMA16(A,B,C) __builtin_amdgcn_mfma_f32_16x16x32_bf16(A, B, C, 0, 0, 0)
#define SPMACC(acc, Ah, Al, Bh, Bl)      \
  acc = MFMA16(Ah, Bh, acc);             \
  acc = MFMA16(Al, Bh, acc);             \
  acc = MFMA16(Ah, Bl, acc);

// ---------------------------------------------------------------------------
// Kernel 1: fused STFT + QK^T + sigmoid + A, all via MFMA. Block = (b,n).
// ---------------------------------------------------------------------------
__global__ __launch_bounds__(512) void stft_mfma_k(const float* __restrict__ x,
                                                   const ushort* __restrict__ WF,
                                                   ushort* __restrict__ ap) {
  __shared__ __align__(16) char smem[133376];
  const int bid = blockIdx.x;
  const int b = bid >> 5, n = bid & 31;
  const int tid = threadIdx.x;
  ushort* xph = reinterpret_cast<ushort*>(smem + 131072);
  ushort* xpl = xph + 576;

  for (int i = tid; i < 576; i += 512) {
    float v = 0.f;
    if (i < 544) {
      int p = i - 32;
      if (p < 0) p = -p;
      if (p >= 480) p = 958 - p;
      v = x[(b * 480 + p) * 32 + n];
    }
    ushort h, l; split_bf(v, h, l);
    xph[i] = h; xpl[i] = l;
  }
  __syncthreads();

  const int wv = tid >> 6, lane = tid & 63;
  const int mt = wv >> 1, nth = wv & 1;
  const int l15 = lane & 15, l4 = lane >> 4;

  bf16x8 WA[2][2][2];  // [cs][part][ks]
#pragma unroll
  for (int cs = 0; cs < 2; ++cs)
#pragma unroll
    for (int part = 0; part < 2; ++part)
#pragma unroll
      for (int ks = 0; ks < 2; ++ks)
        WA[cs][part][ks] = *reinterpret_cast<const bf16x8*>(
            WF + (((cs * 2 + part) * 2 + ks) * 4 + mt) * 512 + lane * 8);

  f32x4 acc1[2][4];
#pragma unroll
  for (int cs = 0; cs < 2; ++cs)
#pragma unroll
    for (int nt = 0; nt < 4; ++nt) acc1[cs][nt] = (f32x4){0.f, 0.f, 0.f, 0.f};

#pragma unroll
  for (int ks = 0; ks < 2; ++ks) {
    bf16x8 bh[4], bl[4];
#pragma unroll
    for (int nt = 0; nt < 4; ++nt) {
      int n_ = ((nth * 4 + nt) * 16) + l15;
      int e = n_ * 4 + ks * 32 + l4 * 8;
      bf16x4 h0 = *reinterpret_cast<const bf16x4*>(xph + e);
      bf16x4 h1 = *reinterpret_cast<const bf16x4*>(xph + e + 4);
      bf16x4 l0 = *reinterpret_cast<const bf16x4*>(xpl + e);
      bf16x4 l1 = *reinterpret_cast<const bf16x4*>(xpl + e + 4);
      bh[nt] = mk8(h0, h1); bl[nt] = mk8(l0, l1);
    }
#pragma unroll
    for (int cs = 0; cs < 2; ++cs)
#pragma unroll
      for (int nt = 0; nt < 4; ++nt) {
        SPMACC(acc1[cs][nt], WA[cs][0][ks], WA[cs][1][ks], bh[nt], bl[nt]);
      }
  }

#pragma unroll
  for (int cs = 0; cs < 2; ++cs)
#pragma unroll
    for (int nt = 0; nt < 4; ++nt) {
      int k = (nth * 4 + nt) * 16 + l15;
      bool kv = (k < 121);
#pragma unroll
      for (int r = 0; r < 4; ++r) {
        int f = mt * 16 + l4 * 4 + r;
        float v = kv ? acc1[cs][nt][r] : 0.f;
        ushort h, l; split_bf(v, h, l);
        int ba = (f << 8) + (k << 1); ba ^= (f & 7) << 4;
        *reinterpret_cast<ushort*>(smem + cs * 32768 + ba) = h;
        *reinterpret_cast<ushort*>(smem + cs * 32768 + 16384 + ba) = l;
        int bt = (k << 7) + (f << 1); bt ^= (k & 7) << 4;
        *reinterpret_cast<ushort*>(smem + 65536 + cs * 32768 + bt) = h;
        *reinterpret_cast<ushort*>(smem + 65536 + cs * 32768 + 16384 + bt) = l;
      }
    }
  __syncthreads();

  f32x4 acc2[2][4];  // [nt][rr, ii, ri, ir]
#pragma unroll
  for (int nt = 0; nt < 2; ++nt)
#pragma unroll
    for (int c = 0; c < 4; ++c) acc2[nt][c] = (f32x4){0.f, 0.f, 0.f, 0.f};

#pragma unroll
  for (int ks = 0; ks < 4; ++ks) {
    bf16x8 A_[2][2];
#pragma unroll
    for (int comp = 0; comp < 2; ++comp)
#pragma unroll
      for (int part = 0; part < 2; ++part) {
        int f = mt * 16 + l15;
        int ba = (f << 8) + ((ks * 32 + l4 * 8) << 1); ba ^= (f & 7) << 4;
        A_[comp][part] = *reinterpret_cast<const bf16x8*>(smem + comp * 32768 + part * 16384 + ba);
      }
    bf16x8 B_[2][2][2];
#pragma unroll
    for (int comp = 0; comp < 2; ++comp)
#pragma unroll
      for (int part = 0; part < 2; ++part)
#pragma unroll
        for (int nt = 0; nt < 2; ++nt) {
          int g = (nth * 2 + nt) * 16 + l15;
          int ba = (g << 8) + ((ks * 32 + l4 * 8) << 1); ba ^= (g & 7) << 4;
          B_[comp][part][nt] = *reinterpret_cast<const bf16x8*>(smem + comp * 32768 + part * 16384 + ba);
        }
#pragma unroll
    for (int nt = 0; nt < 2; ++nt) {
      SPMACC(acc2[nt][0], A_[0][0], A_[0][1], B_[0][0][nt], B_[0][1][nt]);
      SPMACC(acc2[nt][1], A_[1][0], A_[1][1], B_[1][0][nt], B_[1][1][nt]);
      SPMACC(acc2[nt][2], A_[0][0], A_[0][1], B_[1][0][nt], B_[1][1][nt]);
      SPMACC(acc2[nt][3], A_[1][0], A_[1][1], B_[0][0][nt], B_[0][1][nt]);
    }
  }
  __syncthreads();

#pragma unroll
  for (int nt = 0; nt < 2; ++nt) {
    int g = (nth * 2 + nt) * 16 + l15;
#pragma unroll
    for (int r = 0; r < 4; ++r) {
      int f = mt * 16 + l4 * 4 + r;
      float qr = acc2[nt][0][r] - acc2[nt][1][r];
      float qi = acc2[nt][2][r] + acc2[nt][3][r];
      float vr = 1.f / (1.f + __expf(-qr));
      float vi = 1.f / (1.f + __expf(-qi));
      int ba = (f << 7) + (g << 1); ba ^= (f & 7) << 4;
      ushort h, l;
      split_bf(vr, h, l);
      *reinterpret_cast<ushort*>(smem + ba) = h;
      *reinterpret_cast<ushort*>(smem + 8192 + ba) = l;
      split_bf(vi, h, l);
      *reinterpret_cast<ushort*>(smem + 16384 + ba) = h;
      *reinterpret_cast<ushort*>(smem + 24576 + ba) = l;
    }
  }
  __syncthreads();

  f32x4 acc3[4][3];
#pragma unroll
  for (int nt = 0; nt < 4; ++nt)
#pragma unroll
    for (int c = 0; c < 3; ++c) acc3[nt][c] = (f32x4){0.f, 0.f, 0.f, 0.f};

#pragma unroll
  for (int ks = 0; ks < 2; ++ks) {
    bf16x8 QA[2][2];
#pragma unroll
    for (int comp = 0; comp < 2; ++comp)
#pragma unroll
      for (int part = 0; part < 2; ++part) {
        int f = mt * 16 + l15;
        int ba = (f << 7) + ((ks * 32 + l4 * 8) << 1); ba ^= (f & 7) << 4;
        QA[comp][part] = *reinterpret_cast<const bf16x8*>(smem + comp * 16384 + part * 8192 + ba);
      }
#pragma unroll
    for (int nt = 0; nt < 4; ++nt) {
      int k = (nth * 4 + nt) * 16 + l15;
      int bq = (k << 7) + ((ks * 32 + l4 * 8) << 1); bq ^= (k & 7) << 4;
      bf16x8 Srh = *reinterpret_cast<const bf16x8*>(smem + 65536 + bq);
      bf16x8 Srl = *reinterpret_cast<const bf16x8*>(smem + 81920 + bq);
      bf16x8 Sih = *reinterpret_cast<const bf16x8*>(smem + 98304 + bq);
      bf16x8 Sil = *reinterpret_cast<const bf16x8*>(smem + 114688 + bq);
      SPMACC(acc3[nt][0], QA[0][0], QA[0][1], Srh, Srl);
      SPMACC(acc3[nt][1], QA[1][0], QA[1][1], Sih, Sil);
      SPMACC(acc3[nt][2], QA[0][0], QA[0][1], Sih, Sil);
      SPMACC(acc3[nt][2], QA[1][0], QA[1][1], Srh, Srl);
    }
  }
  __syncthreads();

#pragma unroll
  for (int nt = 0; nt < 4; ++nt) {
    int k = (nth * 4 + nt) * 16 + l15;
#pragma unroll
    for (int r = 0; r < 4; ++r) {
      int f = mt * 16 + l4 * 4 + r;
      float ar = acc3[nt][0][r] - acc3[nt][1][r];
      float ai = acc3[nt][2][r];
      int ba = (f << 8) + (k << 1); ba ^= (f & 7) << 4;
      *reinterpret_cast<ushort*>(smem + ba) = f2bf(ar);
      *reinterpret_cast<ushort*>(smem + 16384 + ba) = f2bf(ai);
    }
  }
  __syncthreads();

  uint4* dst = reinterpret_cast<uint4*>(ap);
  for (int i = tid; i < 2048; i += 512) {
    int comp = i >> 10, rem = i & 1023;
    int f = rem >> 4, q = rem & 15;
    uint4 v = *reinterpret_cast<const uint4*>(
        smem + comp * 16384 + (f << 8) + ((q ^ (f & 7)) << 4));
    dst[((size_t)(b * 64 + n + 32 * comp) * 64) * 16 + rem] = v;
  }
}

// ---------------------------------------------------------------------------
// Kernel 2: transpose a_planar -> a_nhwc, FUSED with conv0 (1x1) -> csumA init.
// ---------------------------------------------------------------------------
__global__ __launch_bounds__(256) void transpose_k(const ushort* __restrict__ ap,
    ushort* __restrict__ an, const ushort* __restrict__ AF,
    const float* __restrict__ BB, const float* __restrict__ wl0,
    float* __restrict__ csumA) {
  __shared__ __align__(16) ushort T[64 * 128];
  const int b = blockIdx.x >> 6, h = blockIdx.x & 63;
  const int tid = threadIdx.x;
#pragma unroll
  for (int it = 0; it < 4; ++it) {
    int i = it * 256 + tid;
    int cc = i >> 4, q = i & 15;
    const uint4* src = reinterpret_cast<const uint4*>(ap) +
                       ((size_t)((b * 64 + cc) * 64 + h) * 16 + q);
    *reinterpret_cast<uint4*>(&T[cc * 128 + q * 8]) = *src;
  }
  __syncthreads();
  const int p = tid >> 1, cc0 = (tid & 1) * 32;
  uint ou[16];
#pragma unroll
  for (int it = 0; it < 16; ++it) {
    uint lo = T[(cc0 + 2 * it) * 128 + p];
    uint hi = T[(cc0 + 2 * it + 1) * 128 + p];
    ou[it] = lo | (hi << 16);
  }
  uint4* dst = reinterpret_cast<uint4*>(an + ((size_t)((b * 64 + h) * 128 + p) * 64 + cc0));
#pragma unroll
  for (int r = 0; r < 4; ++r) dst[r] = make_uint4(ou[4*r], ou[4*r+1], ou[4*r+2], ou[4*r+3]);
  __syncthreads();   // all T reads done before overwrite

  // re-stage swizzled [w128][cc64] (conv staging layout) into T's memory
  char* S = reinterpret_cast<char*>(T);
#pragma unroll
  for (int it = 0; it < 16; ++it) {
    int byt = p * 128 + (cc0 + 2 * it) * 2;
    byt ^= (p & 7) << 4;
    *reinterpret_cast<uint*>(S + byt) = ou[it];
  }
  __syncthreads();

  // conv0 MFMA (weights AF conv0, split hi/lo) -> csumA init
  const int wave = tid >> 6, lane = tid & 63;
  const int mtb = wave & 1, ntb = (wave >> 1) * 4;
  const int l15 = lane & 15, l4 = lane >> 4;
  const ushort* Ab = AF + lane * 8;
  bf16x8 AH[2][2], AL[2][2];
#pragma unroll
  for (int ks = 0; ks < 2; ++ks)
#pragma unroll
    for (int mi = 0; mi < 2; ++mi) {
      AH[ks][mi] = *reinterpret_cast<const bf16x8*>(Ab + ks * 2048 + (mtb + 2 * mi) * 512);
      AL[ks][mi] = *reinterpret_cast<const bf16x8*>(Ab + 4096 + ks * 2048 + (mtb + 2 * mi) * 512);
    }
  f32x4 acc[2][4];
#pragma unroll
  for (int mi = 0; mi < 2; ++mi)
#pragma unroll
    for (int nt = 0; nt < 4; ++nt) acc[mi][nt] = (f32x4){0.f, 0.f, 0.f, 0.f};
#pragma unroll
  for (int ks = 0; ks < 2; ++ks) {
    bf16x8 bv[4];
#pragma unroll
    for (int nt = 0; nt < 4; ++nt) {
      int w = (ntb + nt) * 16 + l15;
      int byt = w * 128 + ks * 64 + l4 * 16;
      byt ^= (w & 7) << 4;
      bv[nt] = *reinterpret_cast<const bf16x8*>(S + byt);
    }
#pragma unroll
    for (int nt = 0; nt < 4; ++nt) {
      acc[0][nt] = MFMA16(AH[ks][0], bv[nt], acc[0][nt]);
      acc[1][nt] = MFMA16(AH[ks][1], bv[nt], acc[1][nt]);
    }
#pragma unroll
    for (int nt = 0; nt < 4; ++nt) {
      acc[0][nt] = MFMA16(AL[ks][0], bv[nt], acc[0][nt]);
      acc[1][nt] = MFMA16(AL[ks][1], bv[nt], acc[1][nt]);
    }
  }
  const float w00 = wl0[0], w01 = wl0[1];
#pragma unroll
  for (int nt = 0; nt < 4; ++nt) {
    int gw = (ntb + nt) * 16 + l15;
    if (gw < 121) {
#pragma unroll
      for (int r = 0; r < 4; ++r) {
        int n = mtb * 16 + l4 * 4 + r;
        float rr = acc[0][nt][r] + BB[n];
        float im = acc[1][nt][r] + BB[n + 32];
        csumA[((size_t)(b * 32 + n) * 64 + h) * 121 + gw] =
            (fmaxf(rr, 0.f) * w00 + fmaxf(im, 0.f) * w01) * (1.f / 3.f);
      }
    }
  }
}

// ---------------------------------------------------------------------------
// Kernel 3: prep. Adds zero-page clear (64B) for conv OOB staging.
// ---------------------------------------------------------------------------
__global__ __launch_bounds__(256) void prep_k(
    const float* __restrict__ w0r, const float* __restrict__ w0i,
    const float* __restrict__ b0r, const float* __restrict__ b0i,
    const float* __restrict__ W1r, const float* __restrict__ W1i,
    const float* __restrict__ B1r, const float* __restrict__ B1i,
    const float* __restrict__ W2r, const float* __restrict__ W2i,
    const float* __restrict__ B2r, const float* __restrict__ B2i,
    const float* __restrict__ wl2,
    ushort* __restrict__ AF, ushort* __restrict__ WF, float* __restrict__ BB,
    float* __restrict__ wl2T, float* __restrict__ zpg) {
  const int blk = blockIdx.x, tid = threadIdx.x;
  const float PI32 = 0.0981747704246810387f;

  if (blk == 38) {
    for (int i = tid; i < 121 * 480; i += 256) {
      int k = i / 480, t = i - k * 480;
      wl2T[i] = wl2[t * 121 + k];
    }
    if (tid < 16) zpg[tid] = 0.f;   // 64B zero page
    return;
  }
  if (blk == 37) {
    for (int i = tid; i < 16384; i += 256) {
      int j = i & 7, ln = (i >> 3) & 63, mt = (i >> 9) & 3, ks = (i >> 11) & 1;
      int part = (i >> 12) & 1, cs = (i >> 13) & 1;
      int f = mt * 16 + (ln & 15);
      int t = ks * 32 + (ln >> 4) * 8 + j;
      float win = 0.5f * (1.0f - __cosf(PI32 * (float)t));
      int m = (f * t) & 63;
      float sv, cv;
      __sincosf(PI32 * (float)m, &sv, &cv);
      float val = (cs == 0) ? (win * cv * 0.125f) : (-win * sv * 0.125f);
      ushort h = f2bf(val);
      WF[i] = part ? f2bf(val - bf2f_raw(h)) : h;
    }
    return;
  }

  int conv, tap, TT;
  const float *Wr, *Wi;
  if (blk == 0) { conv = 0; tap = 0; TT = 1; Wr = w0r; Wi = w0i; }
  else {
    int q = blk - 1; conv = 1 + q / 9; tap = q - (q / 9) * 9; TT = 9;
    if (conv == 1)      { Wr = W1r;        Wi = W1i; }
    else if (conv == 2) { Wr = W2r;        Wi = W2i; }
    else if (conv == 3) { Wr = W1r + 9216; Wi = W1i + 9216; }
    else                { Wr = W2r + 9216; Wi = W2i + 9216; }
  }
  ushort thi[16], tlo[16];
#pragma unroll
  for (int jj = 0; jj < 16; ++jj) {
    int e = tid * 16 + jj;
    int j = e & 7, lane_e = (e >> 3) & 63, mt = (e >> 9) & 3, ks = (e >> 11) & 1;
    int o  = mt * 16 + (lane_e & 15);
    int cc = ks * 32 + 8 * (lane_e >> 4) + j;
    int ci = cc & 31, ch = cc >> 5, on = o & 31, oh = o >> 5;
    float wr = Wr[(on * 32 + ci) * TT + tap];
    float wi = Wi[(on * 32 + ci) * TT + tap];
    float v = (oh == 0) ? (ch == 0 ? wr : -wi) : (ch == 0 ? wi : wr);
    ushort h = f2bf(v);
    thi[jj] = h;
    tlo[jj] = f2bf(v - bf2f_raw(h));
  }
  ushort* base = AF + conv * 73728 + tap * 8192 + tid * 16;
  uint4* dh = reinterpret_cast<uint4*>(base);
  uint4* dl = reinterpret_cast<uint4*>(base + 4096);
  dh[0] = *reinterpret_cast<uint4*>(&thi[0]);
  dh[1] = *reinterpret_cast<uint4*>(&thi[8]);
  dl[0] = *reinterpret_cast<uint4*>(&tlo[0]);
  dl[1] = *reinterpret_cast<uint4*>(&tlo[8]);

  if (blk == 0) {
    for (int i = tid; i < 320; i += 256) {
      int c = i >> 6, o = i & 63;
      const float *br, *bi;
      if (c == 0)      { br = b0r;      bi = b0i; }
      else if (c == 1) { br = B1r;      bi = B1i; }
      else if (c == 2) { br = B2r;      bi = B2i; }
      else if (c == 3) { br = B1r + 32; bi = B1i + 32; }
      else             { br = B2r + 32; bi = B2i + 32; }
      BB[c * 64 + o] = (o < 32) ? (br[o] - bi[o]) : (br[o - 32] + bi[o - 32]);
    }
  }
}

// ---------------------------------------------------------------------------
// Conv (R16): 8 LDS row buffers [68 bw][64 cc] bf16, read swizzle ^(bw&7)<<4.
// Buffer r holds input row h0 + r - 2. Block output: 64 ch x 4 h x 64 w.
// Wave tile 2 mt x 8 nt (2h x 4w) [R14]. Staging via global_load_lds:
// linear LDS dest, swizzle folded into per-lane global source (q ^= bw&7),
// OOB lanes read the zero page.
// ---------------------------------------------------------------------------
#define RWB 8704

__device__ __forceinline__ void run_taps9(const char* __restrict__ smem,
    const ushort* __restrict__ afrag, int d,
    int ng, int mtb, int l15, int l4, int lane, f32x4 acc[2][8]) {
  const ushort* Ab = afrag + lane * 8;
#pragma unroll
  for (int t = 0; t < 9; ++t) {
    const int dy = t / 3;
    const int dxo = ((t - dy * 3) - 1) * d;
    const int bufb = (dy - 1) * d + 2 + ng * 2;   // + (nt>>2) selects h row
    const ushort* At = Ab + t * 8192;
    bf16x8 AH[2][2], AL[2][2];  // [ks][mi]
#pragma unroll
    for (int ks = 0; ks < 2; ++ks)
#pragma unroll
      for (int mi = 0; mi < 2; ++mi) {
        AH[ks][mi] = *reinterpret_cast<const bf16x8*>(At + ks * 2048 + (mtb + 2 * mi) * 512);
        AL[ks][mi] = *reinterpret_cast<const bf16x8*>(At + 4096 + ks * 2048 + (mtb + 2 * mi) * 512);
      }
#pragma unroll
    for (int ks = 0; ks < 2; ++ks) {
      bf16x8 bv[8];
#pragma unroll
      for (int nt = 0; nt < 8; ++nt) {
        int bw = (nt & 3) * 16 + l15 + dxo + 2;       // in [0,68)
        int byt = (bufb + (nt >> 2)) * RWB + bw * 128 + ks * 64 + l4 * 16;
        byt ^= (bw & 7) << 4;
        bv[nt] = *reinterpret_cast<const bf16x8*>(smem + byt);
      }
      __builtin_amdgcn_s_setprio(1);
#pragma unroll
      for (int nt = 0; nt < 8; ++nt) {
        acc[0][nt] = MFMA16(AH[ks][0], bv[nt], acc[0][nt]);
        acc[1][nt] = MFMA16(AH[ks][1], bv[nt], acc[1][nt]);
      }
#pragma unroll
      for (int nt = 0; nt < 8; ++nt) {
        acc[0][nt] = MFMA16(AL[ks][0], bv[nt], acc[0][nt]);
        acc[1][nt] = MFMA16(AL[ks][1], bv[nt], acc[1][nt]);
      }
      __builtin_amdgcn_s_setprio(0);
    }
  }
}

__device__ __forceinline__ void conv_body3(char* smem,
    const ushort* __restrict__ xin, ushort* __restrict__ tout,
    const ushort* __restrict__ afrag, const float* __restrict__ bb,
    const float* __restrict__ wl0, float* __restrict__ csum,
    const ushort* __restrict__ zp,
    int d, int b, int h0, int side, int mode, int tid) {
  const int wave = tid >> 6, lane = tid & 63;
  const int mtb = wave & 1;            // M-tiles {mtb, mtb+2} -> rows o, o+32
  const int ng = wave >> 1;            // h-pair group: rows {2ng, 2ng+1}
  const int l15 = lane & 15, l4 = lane >> 4;
  const int wbase = side * 64;

  // ---- global_load_lds staging: linear LDS dest, swizzled global source ----
#pragma unroll
  for (int r = 0; r < 8; ++r) {
    const int hh = h0 + r - 2;
    const bool hv = ((unsigned)hh < 64u);
    const ushort* rowp = xin + ((size_t)(b * 64 + hh) << 13);
#pragma unroll
    for (int c = 0; c < 3; ++c) {
      int i = c * 256 + tid;
      if (i < 544) {
        int bw = i >> 3, q = i & 7;
        int gw = wbase + bw - 2;
        int qs = q ^ (bw & 7);           // swizzle folded into source
        const ushort* src = (hv && (unsigned)gw < 128u)
                                ? (rowp + (size_t)gw * 64 + qs * 8)
                                : zp;
        // wave-uniform LDS base: slot (c*256 + wave*64)*16 within row buffer r
        char* ldsb = smem + r * RWB + ((i & ~63) << 4);
        gld16(src, ldsb);
      }
    }
  }
  __syncthreads();

  f32x4 acc[2][8];
#pragma unroll
  for (int mi = 0; mi < 2; ++mi)
#pragma unroll
    for (int nt = 0; nt < 8; ++nt) acc[mi][nt] = (f32x4){0.f, 0.f, 0.f, 0.f};

  run_taps9(smem, afrag, d, ng, mtb, l15, l4, lane, acc);

  if (mode == 2) {
    __syncthreads();                       // row buffers free -> bounce
    uint* Lb = reinterpret_cast<uint*>(smem);  // [4 jrow][32 opair][66]
#pragma unroll
    for (int mi = 0; mi < 2; ++mi) {
#pragma unroll
      for (int rp = 0; rp < 2; ++rp) {
        int o = (mtb + 2 * mi) * 16 + l4 * 4 + rp * 2;
        float b0 = bb[o], b1 = bb[o + 1];
#pragma unroll
        for (int nt = 0; nt < 8; ++nt) {
          int jrow = ng * 2 + (nt >> 2);
          int wl = (nt & 3) * 16 + l15;
          uint pk = (uint)f2bf(acc[mi][nt][rp * 2] + b0) |
                    ((uint)f2bf(acc[mi][nt][rp * 2 + 1] + b1) << 16);
          Lb[(jrow * 32 + (o >> 1)) * 66 + wl] = pk;
        }
      }
    }
    __syncthreads();
#pragma unroll
    for (int c = 0; c < 8; ++c) {
      int i = c * 256 + tid;           // 2048 uint4 = 4h x 64w x 64cc
      int jrow = i >> 9, rem = i & 511;
      int wl = rem >> 3, q = rem & 7;
      int gw = wbase + wl;
      int hh = h0 + jrow;
      bool val = (gw < 121);
      uint4 v;
      v.x = val ? Lb[(jrow * 32 + q * 4 + 0) * 66 + wl] : 0u;
      v.y = val ? Lb[(jrow * 32 + q * 4 + 1) * 66 + wl] : 0u;
      v.z = val ? Lb[(jrow * 32 + q * 4 + 2) * 66 + wl] : 0u;
      v.w = val ? Lb[(jrow * 32 + q * 4 + 3) * 66 + wl] : 0u;
      *reinterpret_cast<uint4*>(
          tout + (((size_t)(b * 64 + hh) * 128 + gw) * 64 + q * 8)) = v;
    }
  } else {
    const float w00 = wl0[0], w01 = wl0[1];
#pragma unroll
    for (int nt = 0; nt < 8; ++nt) {
      int gw = wbase + (nt & 3) * 16 + l15;
      int hh = h0 + ng * 2 + (nt >> 2);
      if (gw < 121) {
#pragma unroll
        for (int r = 0; r < 4; ++r) {
          int n = mtb * 16 + l4 * 4 + r;
          float rr = acc[0][nt][r] + bb[n];
          float im = acc[1][nt][r] + bb[n + 32];
          float v = (fmaxf(rr, 0.f) * w00 + fmaxf(im, 0.f) * w01) * (1.f / 3.f);
          float* p = csum + ((size_t)(b * 32 + n) * 64 + hh) * 121 + gw;
          if (mode == 1) v += *p;
          *p = v;
        }
      }
    }
  }
}

// D1 (4096 blk): x=bid&7 (XCD), j=bid>>3 (<512): role=j&1, sub=j>>1 (<256),
// wg=(x<<8)|sub -> b=wg>>5, h0, side. Roles+sides adjacent on same XCD.
__global__ __launch_bounds__(256, 2) void convD1_k(
    const ushort* __restrict__ an, ushort* __restrict__ t1, ushort* __restrict__ t2,
    const ushort* __restrict__ AF, const float* __restrict__ BB,
    const float* __restrict__ wl0, const ushort* __restrict__ zp) {
  __shared__ __align__(16) char smem[8 * RWB];
  const int x = blockIdx.x & 7, j = blockIdx.x >> 3;
  const int role = j & 1, sub = j >> 1;
  const int wg = (x << 8) | sub;
  const int b = wg >> 5, rem = wg & 31;
  const int h0 = ((rem >> 1) & 15) * 4, side = rem & 1;
  const int tid = threadIdx.x;
  if (role == 0)
    conv_body3(smem, an, t1, AF + 1 * 73728, BB + 64, wl0, nullptr, zp, 1, b, h0, side, 2, tid);
  else
    conv_body3(smem, an, t2, AF + 3 * 73728, BB + 192, wl0, nullptr, zp, 2, b, h0, side, 2, tid);
}

// D2 (4096 blk): same decode. role0: conv2d1 t1 +=csumA; role1: conv2d2 t2 ->csumB.
__global__ __launch_bounds__(256, 2) void convD2_k(
    const ushort* __restrict__ t1, const ushort* __restrict__ t2,
    const ushort* __restrict__ AF, const float* __restrict__ BB,
    const float* __restrict__ wl0, float* __restrict__ csumA,
    float* __restrict__ csumB, const ushort* __restrict__ zp) {
  __shared__ __align__(16) char smem[8 * RWB];
  const int x = blockIdx.x & 7, j = blockIdx.x >> 3;
  const int role = j & 1, sub = j >> 1;
  const int wg = (x << 8) | sub;
  const int b = wg >> 5, rem = wg & 31;
  const int h0 = ((rem >> 1) & 15) * 4, side = rem & 1;
  const int tid = threadIdx.x;
  if (role == 0)
    conv_body3(smem, t1, nullptr, AF + 2 * 73728, BB + 128, wl0, csumA, zp, 1, b, h0, side, 1, tid);
  else
    conv_body3(smem, t2, nullptr, AF + 4 * 73728, BB + 256, wl0, csumB, zp, 2, b, h0, side, 0, tid);
}

// ---------------------------------------------------------------------------
// Kernel 5: epilogue. h[k] = mean_f(csumA+csumB) + b_l0 ; y = h @ w_l2T + b_l2
// ---------------------------------------------------------------------------
__global__ __launch_bounds__(256) void epi_k(const float* __restrict__ csumA,
    const float* __restrict__ csumB,
    const float* __restrict__ bl0, const float* __restrict__ wl2T,
    const float* __restrict__ bl2, float* __restrict__ out) {
  const int b = blockIdx.x >> 5, n = blockIdx.x & 31;
  __shared__ float sh[121];
  const int tid = threadIdx.x;
  const float* baseA = csumA + (size_t)(b * 32 + n) * 64 * 121;
  const float* baseB = csumB + (size_t)(b * 32 + n) * 64 * 121;
  for (int k = tid; k < 121; k += 256) {
    float s = 0.f;
#pragma unroll 8
    for (int f = 0; f < 64; ++f) s += baseA[f * 121 + k] + baseB[f * 121 + k];
    sh[k] = s * (1.f / 64.f) + bl0[0];
  }
  __syncthreads();
  for (int t = tid; t < 480; t += 256) {
    float acc = bl2[t];
#pragma unroll 8
    for (int k = 0; k < 121; ++k) acc = fmaf(sh[k], wl2T[k * 480 + t], acc);
    out[(b * 480 + t) * 32 + n] = acc;
  }
}

// ---------------------------------------------------------------------------
extern "C" void kernel_launch(void* const* d_in, const int* in_sizes, int n_in,
                              void* d_out, int out_size, void* d_ws, size_t ws_size,
                              hipStream_t stream) {
  const float* x   = (const float*)d_in[0];
  const float* w0r = (const float*)d_in[1];
  const float* w0i = (const float*)d_in[2];
  const float* b0r = (const float*)d_in[3];
  const float* b0i = (const float*)d_in[4];
  const float* W1r = (const float*)d_in[5];
  const float* W1i = (const float*)d_in[6];
  const float* B1r = (const float*)d_in[7];
  const float* B1i = (const float*)d_in[8];
  const float* W2r = (const float*)d_in[9];
  const float* W2i = (const float*)d_in[10];
  const float* B2r = (const float*)d_in[11];
  const float* B2i = (const float*)d_in[12];
  const float* wl0 = (const float*)d_in[13];
  const float* bl0 = (const float*)d_in[14];
  const float* wl2 = (const float*)d_in[15];
  const float* bl2 = (const float*)d_in[16];

  char* ws = (char*)d_ws;
  const size_t MB64 = (size_t)64 << 20;
  ushort* ap    = (ushort*)ws;                       // a_planar -> t2 later
  ushort* t2    = (ushort*)ws;
  ushort* an    = (ushort*)(ws + MB64);              // a_nhwc -> csumB later
  float*  csumB = (float*)(ws + MB64);
  ushort* t1    = (ushort*)(ws + 2 * MB64);
  float*  csumA = (float*)(ws + 3 * MB64);           // [b][32][64][121] fp32
  const size_t CSZ = (size_t)64 * 32 * 64 * 121 * 4; // 63,438,848 B
  ushort* AF   = (ushort*)(ws + 3 * MB64 + CSZ);     // 737,280 B
  ushort* WFp  = AF + 5 * 73728;                     // 32,768 B
  float*  BB   = (float*)(WFp + 16384);              // 1,280 B
  float*  wl2T = BB + 320;                           // 232,320 B
  float*  zpg  = wl2T + 58080;                       // 64 B zero page
  float*  out  = (float*)d_out;

  hipLaunchKernelGGL(prep_k, dim3(39), dim3(256), 0, stream,
                     w0r, w0i, b0r, b0i, W1r, W1i, B1r, B1i, W2r, W2i, B2r, B2i,
                     wl2, AF, WFp, BB, wl2T, zpg);
  hipLaunchKernelGGL(stft_mfma_k, dim3(2048), dim3(512), 0, stream, x, WFp, ap);
  // transpose + fused conv0 -> csumA init
  hipLaunchKernelGGL(transpose_k, dim3(4096), dim3(256), 0, stream,
                     ap, an, AF, BB, wl0, csumA);
  // D1: conv1(d=1) -> t1 ; conv1(d=2) -> t2 (overwrites ap)
  hipLaunchKernelGGL(convD1_k, dim3(4096), dim3(256), 0, stream,
                     an, t1, t2, AF, BB, wl0, (const ushort*)zpg);
  // D2: conv2(d=1) += csumA ; conv2(d=2) -> csumB (overwrites an)
  hipLaunchKernelGGL(convD2_k, dim3(4096), dim3(256), 0, stream,
                     t1, t2, AF, BB, wl0, csumA, csumB, (const ushort*)zpg);
  hipLaunchKernelGGL(epi_k, dim3(2048), dim3(256), 0, stream,
                     csumA, csumB, bl0, wl2T, bl2, out);
}